// Round 5
// baseline (371.708 us; speedup 1.0000x reference)
//
#include <hip/hip_runtime.h>

// CrossTableAttention on MI355X (gfx950)
// T=16 B=1024 D=1024 R=8 H=16 DH=64
//
// R9: force read/MFMA overlap with inline-asm ds_read_b128 fragment loads +
//     explicit counted lgkmcnt + sched_barrier(0) (rule #18 discipline).
//     Per phase: issue k asm reads (for phase p+1), s_waitcnt lgkmcnt(k)
//     (prev phase's reads done, new k in flight), sched_barrier(0), 16 MFMA.
//     Reads rebalanced 4/4/8/8 (B(t+1) split across ph2/ph3); vmcnt ledger:
//     ph0-end VWAIT(4) [A_r1r3(t)], ph1-end VWAIT(2) [B(t+1)],
//     ph2-end VWAIT(2) [A_r0r2(t+1)]; own-vmcnt-then-barrier = cross-wave vis.

typedef unsigned short u16;
typedef __attribute__((ext_vector_type(8))) short short8;   // 8 bf16 = 4 VGPRs
typedef __attribute__((ext_vector_type(4))) float f32x4;

__device__ __forceinline__ float bf2f(u16 u) {
  unsigned int x = ((unsigned int)u) << 16;
  return __uint_as_float(x);
}
__device__ __forceinline__ u16 f2bf(float f) {
  unsigned int x = __float_as_uint(f);
  unsigned int r = (x + 0x7fffu + ((x >> 16) & 1u)) >> 16;   // RNE
  return (u16)r;
}

// async global->LDS, 16B per lane; lds dest is wave-uniform base + lane*16
__device__ __forceinline__ void gld_lds16(const void* g, void* l) {
  __builtin_amdgcn_global_load_lds(
      (const __attribute__((address_space(1))) unsigned int*)(unsigned long long)g,
      (__attribute__((address_space(3))) unsigned int*)(unsigned int)(unsigned long long)l,
      16, 0, 0);
}

#define STR_(x) #x
#define STR(x) STR_(x)
#define VWAIT(N) asm volatile("s_waitcnt vmcnt(" STR(N) ")" ::: "memory")
#define LWAIT(N) asm volatile("s_waitcnt lgkmcnt(" STR(N) ")" ::: "memory")
#define SCHED0   __builtin_amdgcn_sched_barrier(0)
// ds_read_b128 from LDS byte offset base + literal byte offset
#define DSR(dst, base, OFF)                                                    \
  asm volatile("ds_read_b128 %0, %1 offset:" STR(OFF)                          \
               : "=v"(dst) : "v"(base))

// ---------------------------------------------------------------- prep kernels

__global__ void relw_kernel(const float* __restrict__ rel_embs,
                            const float* __restrict__ w_rel,
                            const float* __restrict__ b_rel,
                            float* __restrict__ rel_w) {
  const int tr = blockIdx.x;            // t*8 + r, 128 total
  const float* row = rel_embs + (size_t)tr * 1024;
  const int lane = threadIdx.x;         // 64 threads
  float s = 0.f;
  for (int i = lane; i < 1024; i += 64) s += row[i] * w_rel[i];
  for (int off = 32; off > 0; off >>= 1) s += __shfl_down(s, off, 64);
  if (lane == 0) rel_w[tr] = 1.f / (1.f + __expf(-(s + b_rel[0])));
}

__global__ void cvt_f32_bf16(const float* __restrict__ in, u16* __restrict__ out, int n4) {
  int i = blockIdx.x * blockDim.x + threadIdx.x;
  if (i >= n4) return;
  float4 v = ((const float4*)in)[i];
  ushort4 o;
  o.x = f2bf(v.x); o.y = f2bf(v.y); o.z = f2bf(v.z); o.w = f2bf(v.w);
  ((ushort4*)out)[i] = o;
}

// all four 1024x1024 weight matrices in one launch: 4*262144 float4's
__global__ void cvt_w4(const float* __restrict__ Wq, const float* __restrict__ Wk,
                       const float* __restrict__ Wv, const float* __restrict__ Wo,
                       u16* __restrict__ Wcat, u16* __restrict__ Wob) {
  const int i = blockIdx.x * 256 + threadIdx.x;     // 0 .. 1048575
  const int w = i >> 18;                            // 262144 float4 per matrix
  const int j = i & 0x3ffff;
  const float* src = (w == 0) ? Wq : (w == 1) ? Wk : (w == 2) ? Wv : Wo;
  u16* dst = (w == 3) ? Wob : (Wcat + ((size_t)w << 20));
  float4 v = ((const float4*)src)[j];
  ushort4 o;
  o.x = f2bf(v.x); o.y = f2bf(v.y); o.z = f2bf(v.z); o.w = f2bf(v.w);
  ((ushort4*)dst)[j] = o;
}

// ---------------------------------------------------------------- 256^2 mainloop
// A [M,1024] row-major bf16, B [N,1024] row-major bf16 (out = x@W.T), K=1024.
// Block tile 256x256, BK=64, 512 threads = 8 waves (2M x 4N), wave 128x64 out.
// LDS 128KiB: buf0{A,B} buf1{A,B}, each region 256 rows x 64 bf16 (128B/row).
// Swizzle: 16B chunk c of row r lives at physical chunk c ^ (r&7).
// A-frag ledger: phase q needs A-rows wm*128+32q+[0,32) -> stage loads
// {r0,r2} cover phases {0,1}, {r1,r3} cover {2,3} (per wm-half).
// Read-ahead: phase p issues asm ds_reads for phase p+1; B(t+1) split halves
// at ph2/ph3. MFMA waits counted lgkmcnt(k)=this-phase reads in flight.

__device__ __forceinline__ void mainloop256(const u16* __restrict__ A,
                                            const u16* __restrict__ B,
                                            u16* lds, int m0, int n0,
                                            f32x4 (&acc)[8][4]) {
  const int tid  = threadIdx.x;          // 512
  const int lane = tid & 63;
  const int w    = tid >> 6;             // 8 waves
  const int wm   = w >> 2, wn = w & 3;
  const int fr   = lane & 15, fq = lane >> 4;
  const int swz  = fr & 7;

  const unsigned A0 = 0, B0 = 16384, A1 = 32768, B1 = 49152;  // u16 offsets

  // staging descriptors: row&7 and pc are r-invariant (r step = 64 rows)
  const int srow = tid >> 3;                       // row for slot r=0
  const int lc   = (tid & 7) ^ (srow & 7);         // logical chunk stored here
  const u16* a0p = A + (size_t)(m0 + srow) * 1024 + lc * 8;
  const u16* b0p = B + (size_t)(n0 + srow) * 1024 + lc * 8;
  const unsigned d0 = (unsigned)((tid & ~63) * 8); // wave-uniform dest (u16)

  // fragment read base LDS byte offsets per (buffer, ksub)
  unsigned uA0k0, uA0k1, uA1k0, uA1k1, uB0k0, uB0k1, uB1k0, uB1k1;
  {
    const unsigned ck0 = (unsigned)(((0 + fq) ^ swz) << 3);
    const unsigned ck1 = (unsigned)(((4 + fq) ^ swz) << 3);
    const unsigned ar = (unsigned)((wm * 128 + fr) * 64);
    const unsigned br = (unsigned)((wn * 64 + fr) * 64);
    uA0k0 = (A0 + ar + ck0) * 2;  uA0k1 = (A0 + ar + ck1) * 2;
    uA1k0 = (A1 + ar + ck0) * 2;  uA1k1 = (A1 + ar + ck1) * 2;
    uB0k0 = (B0 + br + ck0) * 2;  uB0k1 = (B0 + br + ck1) * 2;
    uB1k0 = (B1 + br + ck0) * 2;  uB1k1 = (B1 + br + ck1) * 2;
  }

  // fragment register files: afA/afB = phase-parity A sets; bfr[tp] = B sets
  short8 afA[4], afB[4], bfr[2][8];

#define STAGE_B4(BO)                                                           \
  do {                                                                         \
    gld_lds16(b0p + 0 * 65536, lds + (BO) + d0 + 0 * 4096);                    \
    gld_lds16(b0p + 1 * 65536, lds + (BO) + d0 + 1 * 4096);                    \
    gld_lds16(b0p + 2 * 65536, lds + (BO) + d0 + 2 * 4096);                    \
    gld_lds16(b0p + 3 * 65536, lds + (BO) + d0 + 3 * 4096);                    \
    b0p += 64;                                                                 \
  } while (0)

#define STAGE_A2(ra, rb, AO)                                                   \
  do {                                                                         \
    gld_lds16(a0p + (ra) * 65536, lds + (AO) + d0 + (ra) * 4096);              \
    gld_lds16(a0p + (rb) * 65536, lds + (AO) + d0 + (rb) * 4096);              \
  } while (0)

// A-frag quad for phase q from buffer bases (bk0,bk1): offsets 4096q, +2048
#define RD_A2(dst, bk0, bk1, O0, O1)                                           \
  do {                                                                         \
    DSR(dst[0], bk0, O0); DSR(dst[1], bk0, O1);                                \
    DSR(dst[2], bk1, O0); DSR(dst[3], bk1, O1);                                \
  } while (0)

// B-frag half (two n-frags j,j+1) from bases: bfr[TB][2j+ks]
#define RD_B2(TB, bk0, bk1, O0, O1, I0)                                        \
  do {                                                                         \
    DSR(bfr[TB][(I0)+0], bk0, O0); DSR(bfr[TB][(I0)+1], bk1, O0);              \
    DSR(bfr[TB][(I0)+2], bk0, O1); DSR(bfr[TB][(I0)+3], bk1, O1);              \
  } while (0)

#define MFMA_PH(q, S, TB)                                                      \
  do {                                                                         \
    __builtin_amdgcn_s_setprio(1);                                             \
    _Pragma("unroll")                                                          \
    for (int j = 0; j < 4; ++j) {                                              \
      acc[2*(q)][j]   = __builtin_amdgcn_mfma_f32_16x16x32_bf16(S[0], bfr[TB][2*j], acc[2*(q)][j],   0, 0, 0); \
      acc[2*(q)+1][j] = __builtin_amdgcn_mfma_f32_16x16x32_bf16(S[1], bfr[TB][2*j], acc[2*(q)+1][j], 0, 0, 0); \
    }                                                                          \
    _Pragma("unroll")                                                          \
    for (int j = 0; j < 4; ++j) {                                              \
      acc[2*(q)][j]   = __builtin_amdgcn_mfma_f32_16x16x32_bf16(S[2], bfr[TB][2*j+1], acc[2*(q)][j],   0, 0, 0); \
      acc[2*(q)+1][j] = __builtin_amdgcn_mfma_f32_16x16x32_bf16(S[3], bfr[TB][2*j+1], acc[2*(q)+1][j], 0, 0, 0); \
    }                                                                          \
    __builtin_amdgcn_s_setprio(0);                                             \
  } while (0)

#define BAR __builtin_amdgcn_s_barrier()

// steady-state K-tile. aC*/aN* = cur/next A bases, bN* = next B bases,
// TBC/TBN = B parities, AO_N/BO_N = next-buffer stage regions.
#define KTILE(aC0, aC1, aN0, aN1, bN0, bN1, TBC, TBN, AO_N, BO_N)              \
  do {                                                                         \
    /* ph0: MFMA q0 (afA); read q1 -> afB; stage B(t+1) */                     \
    RD_A2(afB, aC0, aC1, 4096, 6144);                                          \
    STAGE_B4(BO_N);                                                            \
    LWAIT(4); SCHED0;                                                          \
    MFMA_PH(0, afA, TBC); SCHED0;                                              \
    VWAIT(4);                          /* A_r1,r3(cur) landed */               \
    BAR;                                                                       \
    /* ph1: MFMA q1 (afB); read q2 -> afA; stage A r0,r2 */                    \
    RD_A2(afA, aC0, aC1, 8192, 10240);                                         \
    STAGE_A2(0, 2, AO_N);                                                      \
    LWAIT(4); SCHED0;                                                          \
    MFMA_PH(1, afB, TBC); SCHED0;                                              \
    VWAIT(2);                          /* B(t+1) landed */                     \
    BAR;                                                                       \
    /* ph2: MFMA q2 (afA); read q3 -> afB + B(t+1) half0; stage A r1,r3 */     \
    RD_A2(afB, aC0, aC1, 12288, 14336);                                        \
    RD_B2(TBN, bN0, bN1, 0, 2048, 0);                                          \
    STAGE_A2(1, 3, AO_N); a0p += 64;                                           \
    LWAIT(8); SCHED0;                                                          \
    MFMA_PH(2, afA, TBC); SCHED0;                                              \
    VWAIT(2);                          /* A_r0,r2(t+1) landed */               \
    BAR;                                                                       \
    /* ph3: MFMA q3 (afB); read next q0 -> afA + B(t+1) half1 */               \
    RD_A2(afA, aN0, aN1, 0, 2048);                                             \
    RD_B2(TBN, bN0, bN1, 4096, 6144, 4);                                       \
    LWAIT(8); SCHED0;                                                          \
    MFMA_PH(3, afB, TBC); SCHED0;                                              \
    BAR;                                                                       \
  } while (0)

// last K-tile: no staging, no next-tile reads; drain leftover A_r1,r3
#define KTILE_LAST(aC0, aC1, TBC)                                              \
  do {                                                                         \
    RD_A2(afB, aC0, aC1, 4096, 6144);                                          \
    LWAIT(4); SCHED0;                                                          \
    MFMA_PH(0, afA, TBC); SCHED0;                                              \
    VWAIT(0);                                                                  \
    BAR;                                                                       \
    RD_A2(afA, aC0, aC1, 8192, 10240);                                         \
    LWAIT(4); SCHED0;                                                          \
    MFMA_PH(1, afB, TBC); SCHED0;                                              \
    BAR;                                                                       \
    RD_A2(afB, aC0, aC1, 12288, 14336);                                        \
    LWAIT(4); SCHED0;                                                          \
    MFMA_PH(2, afA, TBC); SCHED0;                                              \
    BAR;                                                                       \
    LWAIT(0); SCHED0;                                                          \
    MFMA_PH(3, afB, TBC);                                                      \
  } while (0)

  // prologue: stage tile 0 -> buf0 in order B0-3, A_r0, A_r2, A_r1, A_r3
  gld_lds16(b0p + 0 * 65536, lds + B0 + d0 + 0 * 4096);
  gld_lds16(b0p + 1 * 65536, lds + B0 + d0 + 1 * 4096);
  gld_lds16(b0p + 2 * 65536, lds + B0 + d0 + 2 * 4096);
  gld_lds16(b0p + 3 * 65536, lds + B0 + d0 + 3 * 4096);
  gld_lds16(a0p + 0 * 65536, lds + A0 + d0 + 0 * 4096);
  gld_lds16(a0p + 2 * 65536, lds + A0 + d0 + 2 * 4096);
  gld_lds16(a0p + 1 * 65536, lds + A0 + d0 + 1 * 4096);
  gld_lds16(a0p + 3 * 65536, lds + A0 + d0 + 3 * 4096);
  a0p += 64; b0p += 64;
  VWAIT(2);                       // B(0)+A_r0,r2 landed; A_r1,r3 in flight
  BAR;
  // pre-read tile0: full B set (parity 0) + ph0 A-frags
  RD_B2(0, uB0k0, uB0k1, 0, 2048, 0);
  RD_B2(0, uB0k0, uB0k1, 4096, 6144, 4);
  RD_A2(afA, uA0k0, uA0k1, 0, 2048);

  for (int it = 0; it < 7; ++it) {       // tiles 0..13
    KTILE(uA0k0, uA0k1, uA1k0, uA1k1, uB1k0, uB1k1, 0, 1, A1, B1);
    KTILE(uA1k0, uA1k1, uA0k0, uA0k1, uB0k0, uB0k1, 1, 0, A0, B0);
  }
  KTILE(uA0k0, uA0k1, uA1k0, uA1k1, uB1k0, uB1k1, 0, 1, A1, B1);  // tile 14
  KTILE_LAST(uA1k0, uA1k1, 1);                                    // tile 15

#undef STAGE_B4
#undef STAGE_A2
#undef RD_A2
#undef RD_B2
#undef MFMA_PH
#undef BAR
#undef KTILE
#undef KTILE_LAST
}

// bijective XCD swizzle for nwg % 8 == 0
__device__ __forceinline__ void xcd_swizzle(int nx, int ny, int& bx, int& by) {
  const int nwg = nx * ny;
  int bid = by * nx + bx;
  bid = (bid & 7) * (nwg >> 3) + (bid >> 3);
  bx = bid % nx;
  by = bid / nx;
}

// GEMM1: X[16384,1024] @ Wcat[3072,1024].T -> Q/K/V stored TRANSPOSED [t][d][b]
__global__ __launch_bounds__(512, 1)
void gemm_qkv(const u16* __restrict__ A, const u16* __restrict__ Bw,
              const float* __restrict__ bq,
              u16* __restrict__ Qt, u16* __restrict__ Kt, u16* __restrict__ Vt) {
  __shared__ __align__(16) u16 lds[65536];   // 128 KiB
  int bx = blockIdx.x, by = blockIdx.y;
  xcd_swizzle(gridDim.x, gridDim.y, bx, by);
  const int n0 = bx * 256;                   // d within QKV-cat (256|1024 ok)
  const int m0 = by * 256;                   // t*1024 + b (256|1024 ok)
  f32x4 acc[8][4];
#pragma unroll
  for (int i = 0; i < 8; ++i)
#pragma unroll
    for (int j = 0; j < 4; ++j) acc[i][j] = (f32x4){0.f, 0.f, 0.f, 0.f};

  mainloop256(A, Bw, lds, m0, n0, acc);
  __syncthreads();   // real fence: all LDS reads retired before scatter reuse

  const int tid  = threadIdx.x;
  const int lane = tid & 63;
  const int w    = tid >> 6;
  const int wm   = w >> 2, wn = w & 3;
  const int colw = lane & 15, roww = (lane >> 4) * 4;
  const int t = m0 >> 10, b0 = m0 & 1023;
  const int sel = n0 >> 10, dbase = n0 & 1023;
  u16* outp = (sel == 0) ? Qt : (sel == 1) ? Kt : Vt;

  // scatter BOTH wm-halves concurrently: region[wm] = 64KiB at wm*32768 u16.
  // phys byte in region = d*256 + (Lbyte ^ ((d&7)<<4)); paired 8B stores.
  {
    char* reg = (char*)(lds + wm * 32768);
#pragma unroll
    for (int j = 0; j < 4; ++j) {
      const int dl = wn * 64 + j * 16 + colw;
      const float badd = (sel == 0) ? bq[dbase + dl] : 0.f;
      char* rowp = reg + (unsigned)dl * 256;
      const unsigned sx = ((unsigned)dl & 7) << 4;
#pragma unroll
      for (int i = 0; i < 8; ++i) {
        const int bl = i * 16 + roww;           // multiple of 4
        uint2 pv;
        pv.x = (unsigned)f2bf(acc[i][j][0] + badd)
             | ((unsigned)f2bf(acc[i][j][1] + badd) << 16);
        pv.y = (unsigned)f2bf(acc[i][j][2] + badd)
             | ((unsigned)f2bf(acc[i][j][3] + badd) << 16);
        *(uint2*)(rowp + (((unsigned)bl * 2) ^ sx)) = pv;
      }
    }
  }
  __syncthreads();
  // writeout: 2 regions x 4096 uint4, coalesced rows into [t][d][b]
#pragma unroll
  for (int pass = 0; pass < 2; ++pass) {
    const char* regp = (const char*)(lds + pass * 32768);
#pragma unroll
    for (int rr = 0; rr < 8; ++rr) {
      const int slot = rr * 512 + tid;          // 4096 slots = 256 rows x 16
      const int row = slot >> 4, c16 = slot & 15;
      const uint4 v = *(const uint4*)(regp + (unsigned)row * 256
                                      + (((unsigned)c16 * 16) ^ (((unsigned)row & 7) << 4)));
      *(uint4*)(outp + ((size_t)t << 20) + (size_t)(dbase + row) * 1024
                + b0 + pass * 128 + c16 * 8) = v;
    }
  }
}

// GEMM2: ctx[16384,1024] @ Wo[1024,1024].T + bo -> fp32 out
__global__ __launch_bounds__(512, 1)
void gemm_out(const u16* __restrict__ A, const u16* __restrict__ Bw,
              const float* __restrict__ bo, float* __restrict__ out) {
  __shared__ __align__(16) u16 lds[65536];
  int bx = blockIdx.x, by = blockIdx.y;
  xcd_swizzle(gridDim.x, gridDim.y, bx, by);
  const int n0 = bx * 256;
  const int m0 = by * 256;
  f32x4 acc[8][4];
#pragma unroll
  for (int i = 0; i < 8; ++i)
#pragma unroll
    for (int j = 0; j < 4; ++j) acc[i][j] = (f32x4){0.f, 0.f, 0.f, 0.f};

  mainloop256(A, Bw, lds, m0, n0, acc);
  // epilogue touches no LDS -> no extra fence needed

  const int lane = threadIdx.x & 63;
  const int w    = threadIdx.x >> 6;
  const int wm   = w >> 2, wn = w & 3;
  const int colw = lane & 15, roww = (lane >> 4) * 4;
#pragma unroll
  for (int j = 0; j < 4; ++j) {
    const int gn = n0 + wn * 64 + j * 16 + colw;
    const float bov = bo[gn];
#pragma unroll
    for (int i = 0; i < 8; ++i) {
      const int gm = m0 + wm * 128 + i * 16 + roww;
#pragma unroll
      for (int r = 0; r < 4; ++r)
        out[(size_t)(gm + r) * 1024 + gn] = acc[i][j][r] + bov;
    }
  }
}

// ---------------------------------------------------------------- attention
// attn5: ONE b per thread (262144 threads = 4096 waves = 16 waves/CU).
// Streams d; loads are 2B/lane (128B/wave contiguous). acc[8] in regs.
// Output staged per 32-d half via LDS (pad 34 -> 2-way banks), coalesced rows.
__global__ __launch_bounds__(256)
void attn5(const u16* __restrict__ Qt, const u16* __restrict__ Kt,
           const u16* __restrict__ Vt,
           const float* __restrict__ relw, const int* __restrict__ rel_idx,
           const float* __restrict__ bk, const float* __restrict__ bv,
           u16* __restrict__ ctx) {
  const int tid = threadIdx.x;
  const int h = blockIdx.y, t = blockIdx.z;
  const int b0 = blockIdx.x * 256;          // block covers b0 .. b0+255
  const int b = b0 + tid;
  const int hd = h * 64;

  __shared__ u16  st[256 * 34];             // [256 b][32 d + 2 pad]  17.0KB
  __shared__ float bks[64], bvs[64], rws[8];
  __shared__ int   rids[8];

  if (tid < 64) { bks[tid] = bk[hd + tid]; bvs[tid] = bv[hd + tid]; }
  else if (tid < 72) { rws[tid - 64] = relw[t * 8 + (tid - 64)];
                       rids[tid - 64] = rel_idx[t * 8 + (tid - 64)]; }
  __syncthreads();

  // element offsets at d=0 into [t][1024 d][1024 b] arrays
  const unsigned qoff = ((unsigned)t << 20) + ((unsigned)hd << 10) + (unsigned)b;
  unsigned koff[8];
#pragma unroll
  for (int r = 0; r < 8; ++r)
    koff[r] = ((unsigned)rids[r] << 20) + ((unsigned)hd << 10) + (unsigned)b;

  // ---- scores
  float acc[8];
#pragma unroll
  for (int r = 0; r < 8; ++r) acc[r] = 0.f;
  float qbk = 0.f;
#pragma unroll 4
  for (int d = 0; d < 64; ++d) {
    const float q = bf2f(Qt[qoff + d * 1024]);
    qbk += q * bks[d];
#pragma unroll
    for (int r = 0; r < 8; ++r)
      acc[r] += q * bf2f(Kt[koff[r] + d * 1024]);
  }

  // ---- softmax -> w[r] = attn_r * rw_r
  float w[8];
  {
    float s[8], mx = -1e30f;
#pragma unroll
    for (int r = 0; r < 8; ++r) {
      s[r] = (rws[r] * acc[r] + qbk) * 0.125f;
      mx = fmaxf(mx, s[r]);
    }
    float sum = 0.f;
#pragma unroll
    for (int r = 0; r < 8; ++r) { s[r] = __expf(s[r] - mx); sum += s[r]; }
    const float inv = 1.f / sum;
#pragma unroll
    for (int r = 0; r < 8; ++r) w[r] = s[r] * inv * rws[r];
  }

  // ---- context: two 32-d halves; stage [b][d] in LDS, coalesced writeout
  for (int half = 0; half < 2; ++half) {
#pragma unroll
    for (int dp = 0; dp < 32; dp += 2) {
      const int d = half * 32 + dp;
      float o0 = bvs[d];
      float o1 = bvs[d + 1];
#pragma unroll
      for (int r = 0; r < 8; ++r) {
        o0 += w[r] * bf2f(Vt[koff[r] + d * 1024]);
        o1 += w[r] * bf2f(Vt[koff[r] + (d + 1) * 1024]);
      }
      const unsigned p = (unsigned)f2bf(o0) | ((unsigned)f2bf(o1) << 16);
      *(unsigned*)(st + tid * 34 + dp) = p;   // byte 68*tid+2dp, 4B-aligned
    }
    __syncthreads();
    // writeout: 256 rows x 64B (32 d); 8 lanes x 8B per row, 8 passes
    {
      const int sub = tid & 7;
      const int rbase = tid >> 3;              // 0..31
#pragma unroll
      for (int p = 0; p < 8; ++p) {
        const int row = p * 32 + rbase;
        const uint2 v = *(const uint2*)(st + row * 34 + sub * 4);
        *(uint2*)(ctx + ((size_t)(t * 1024 + b0 + row)) * 1024
                  + hd + half * 32 + sub * 4) = v;
      }
    }
    __syncthreads();   // st reused by next half
  }
}

// ---------------------------------------------------------------- launch

extern "C" void kernel_launch(void* const* d_in, const int* in_sizes, int n_in,
                              void* d_out, int out_size, void* d_ws, size_t ws_size,
                              hipStream_t stream) {
  const float* table = (const float*)d_in[0];
  const float* rele  = (const float*)d_in[1];
  const int*   ridx  = (const int*)d_in[2];
  const float* Wq    = (const float*)d_in[3];
  const float* bq    = (const float*)d_in[4];
  const float* Wk    = (const float*)d_in[5];
  const float* bk    = (const float*)d_in[6];
  const float* Wv    = (const float*)d_in[7];
  const float* bv    = (const float*)d_in[8];
  const float* Wo    = (const float*)d_in[9];
  const float* bo    = (const float*)d_in[10];
  const float* wr    = (const float*)d_in[11];
  const float* br    = (const float*)d_in[12];
  float* out = (float*)d_out;

  char* ws = (char*)d_ws;
  const size_t MB = 1024 * 1024;
  u16*  Xbf  = (u16*)(ws);                    // 32 MB  [16384,1024] bf16 (also ctx)
  u16*  Kt   = (u16*)(ws + 32  * MB);         // 32 MB  [16][1024 d][1024 b]
  u16*  Vt   = (u16*)(ws + 64  * MB);         // 32 MB
  u16*  Qt   = (u16*)(ws + 96  * MB);         // 32 MB
  u16*  Wcat = (u16*)(ws + 128 * MB);         // 6 MB   [3072,1024] (Wq|Wk|Wv)
  u16*  Wob  = (u16*)(ws + 134 * MB);         // 2 MB
  float* relw = (float*)(ws + 136 * MB);      // 512 B
  u16*  ctxb = Xbf;                           // reuse: Xbf dead after gemm_qkv

  relw_kernel<<<128, 64, 0, stream>>>(rele, wr, br, relw);
  cvt_f32_bf16<<<16384, 256, 0, stream>>>(table, Xbf, 4194304);
  cvt_w4<<<4096, 256, 0, stream>>>(Wq, Wk, Wv, Wo, Wcat, Wob);

  gemm_qkv<<<dim3(12, 64), 512, 0, stream>>>(Xbf, Wcat, bq, Qt, Kt, Vt);
  attn5<<<dim3(4, 16, 16), 256, 0, stream>>>(Qt, Kt, Vt, relw, ridx, bk, bv, ctxb);
  gemm_out<<<dim3(4, 64), 512, 0, stream>>>(ctxb, Wob, bo, out);
}

// Round 6
// 363.835 us; speedup vs baseline: 1.0216x; 1.0216x over previous
//
#include <hip/hip_runtime.h>

// CrossTableAttention on MI355X (gfx950)
// T=16 B=1024 D=1024 R=8 H=16 DH=64
//
// R10: attention restructure (attn6). Pipeline arithmetic showed attn5 was
//      ~200us (54% of total), not the GEMMs. attn6: one block per (t,h)
//      (256 blocks x 512 thr, 2 b per thread, uint loads) -> each (t,h)'s
//      2MB K/V rel-slice read ONCE (was 4x across 4 XCDs); h->XCD grouping
//      so the 16 same-h blocks stream the same 4MB table-slice through one
//      XCD's L2 in lockstep. Logical traffic 2.2GB -> ~0.6GB, LLC->L2
//      ~128MB. GEMMs unchanged from R9.

typedef unsigned short u16;
typedef __attribute__((ext_vector_type(8))) short short8;   // 8 bf16 = 4 VGPRs
typedef __attribute__((ext_vector_type(4))) float f32x4;

__device__ __forceinline__ float bf2f(u16 u) {
  unsigned int x = ((unsigned int)u) << 16;
  return __uint_as_float(x);
}
__device__ __forceinline__ float lo_f(unsigned v) { return __uint_as_float(v << 16); }
__device__ __forceinline__ float hi_f(unsigned v) { return __uint_as_float(v & 0xffff0000u); }
__device__ __forceinline__ u16 f2bf(float f) {
  unsigned int x = __float_as_uint(f);
  unsigned int r = (x + 0x7fffu + ((x >> 16) & 1u)) >> 16;   // RNE
  return (u16)r;
}

// async global->LDS, 16B per lane; lds dest is wave-uniform base + lane*16
__device__ __forceinline__ void gld_lds16(const void* g, void* l) {
  __builtin_amdgcn_global_load_lds(
      (const __attribute__((address_space(1))) unsigned int*)(unsigned long long)g,
      (__attribute__((address_space(3))) unsigned int*)(unsigned int)(unsigned long long)l,
      16, 0, 0);
}

#define STR_(x) #x
#define STR(x) STR_(x)
#define VWAIT(N) asm volatile("s_waitcnt vmcnt(" STR(N) ")" ::: "memory")
#define LWAIT(N) asm volatile("s_waitcnt lgkmcnt(" STR(N) ")" ::: "memory")
#define SCHED0   __builtin_amdgcn_sched_barrier(0)
// ds_read_b128 from LDS byte offset base + literal byte offset
#define DSR(dst, base, OFF)                                                    \
  asm volatile("ds_read_b128 %0, %1 offset:" STR(OFF)                          \
               : "=v"(dst) : "v"(base))

// ---------------------------------------------------------------- prep kernels

__global__ void relw_kernel(const float* __restrict__ rel_embs,
                            const float* __restrict__ w_rel,
                            const float* __restrict__ b_rel,
                            float* __restrict__ rel_w) {
  const int tr = blockIdx.x;            // t*8 + r, 128 total
  const float* row = rel_embs + (size_t)tr * 1024;
  const int lane = threadIdx.x;         // 64 threads
  float s = 0.f;
  for (int i = lane; i < 1024; i += 64) s += row[i] * w_rel[i];
  for (int off = 32; off > 0; off >>= 1) s += __shfl_down(s, off, 64);
  if (lane == 0) rel_w[tr] = 1.f / (1.f + __expf(-(s + b_rel[0])));
}

__global__ void cvt_f32_bf16(const float* __restrict__ in, u16* __restrict__ out, int n4) {
  int i = blockIdx.x * blockDim.x + threadIdx.x;
  if (i >= n4) return;
  float4 v = ((const float4*)in)[i];
  ushort4 o;
  o.x = f2bf(v.x); o.y = f2bf(v.y); o.z = f2bf(v.z); o.w = f2bf(v.w);
  ((ushort4*)out)[i] = o;
}

// all four 1024x1024 weight matrices in one launch: 4*262144 float4's
__global__ void cvt_w4(const float* __restrict__ Wq, const float* __restrict__ Wk,
                       const float* __restrict__ Wv, const float* __restrict__ Wo,
                       u16* __restrict__ Wcat, u16* __restrict__ Wob) {
  const int i = blockIdx.x * 256 + threadIdx.x;     // 0 .. 1048575
  const int w = i >> 18;                            // 262144 float4 per matrix
  const int j = i & 0x3ffff;
  const float* src = (w == 0) ? Wq : (w == 1) ? Wk : (w == 2) ? Wv : Wo;
  u16* dst = (w == 3) ? Wob : (Wcat + ((size_t)w << 20));
  float4 v = ((const float4*)src)[j];
  ushort4 o;
  o.x = f2bf(v.x); o.y = f2bf(v.y); o.z = f2bf(v.z); o.w = f2bf(v.w);
  ((ushort4*)dst)[j] = o;
}

// ---------------------------------------------------------------- 256^2 mainloop
// A [M,1024] row-major bf16, B [N,1024] row-major bf16 (out = x@W.T), K=1024.
// Block tile 256x256, BK=64, 512 threads = 8 waves (2M x 4N), wave 128x64 out.
// LDS 128KiB: buf0{A,B} buf1{A,B}, each region 256 rows x 64 bf16 (128B/row).
// Swizzle: 16B chunk c of row r lives at physical chunk c ^ (r&7).
// Read-ahead by one phase with inline-asm ds_read + counted lgkm waits.

__device__ __forceinline__ void mainloop256(const u16* __restrict__ A,
                                            const u16* __restrict__ B,
                                            u16* lds, int m0, int n0,
                                            f32x4 (&acc)[8][4]) {
  const int tid  = threadIdx.x;          // 512
  const int lane = tid & 63;
  const int w    = tid >> 6;             // 8 waves
  const int wm   = w >> 2, wn = w & 3;
  const int fr   = lane & 15, fq = lane >> 4;
  const int swz  = fr & 7;

  const unsigned A0 = 0, B0 = 16384, A1 = 32768, B1 = 49152;  // u16 offsets

  // staging descriptors: row&7 and pc are r-invariant (r step = 64 rows)
  const int srow = tid >> 3;                       // row for slot r=0
  const int lc   = (tid & 7) ^ (srow & 7);         // logical chunk stored here
  const u16* a0p = A + (size_t)(m0 + srow) * 1024 + lc * 8;
  const u16* b0p = B + (size_t)(n0 + srow) * 1024 + lc * 8;
  const unsigned d0 = (unsigned)((tid & ~63) * 8); // wave-uniform dest (u16)

  // fragment read base LDS byte offsets per (buffer, ksub)
  unsigned uA0k0, uA0k1, uA1k0, uA1k1, uB0k0, uB0k1, uB1k0, uB1k1;
  {
    const unsigned ck0 = (unsigned)(((0 + fq) ^ swz) << 3);
    const unsigned ck1 = (unsigned)(((4 + fq) ^ swz) << 3);
    const unsigned ar = (unsigned)((wm * 128 + fr) * 64);
    const unsigned br = (unsigned)((wn * 64 + fr) * 64);
    uA0k0 = (A0 + ar + ck0) * 2;  uA0k1 = (A0 + ar + ck1) * 2;
    uA1k0 = (A1 + ar + ck0) * 2;  uA1k1 = (A1 + ar + ck1) * 2;
    uB0k0 = (B0 + br + ck0) * 2;  uB0k1 = (B0 + br + ck1) * 2;
    uB1k0 = (B1 + br + ck0) * 2;  uB1k1 = (B1 + br + ck1) * 2;
  }

  // fragment register files: afA/afB = phase-parity A sets; bfr[tp] = B sets
  short8 afA[4], afB[4], bfr[2][8];

#define STAGE_B4(BO)                                                           \
  do {                                                                         \
    gld_lds16(b0p + 0 * 65536, lds + (BO) + d0 + 0 * 4096);                    \
    gld_lds16(b0p + 1 * 65536, lds + (BO) + d0 + 1 * 4096);                    \
    gld_lds16(b0p + 2 * 65536, lds + (BO) + d0 + 2 * 4096);                    \
    gld_lds16(b0p + 3 * 65536, lds + (BO) + d0 + 3 * 4096);                    \
    b0p += 64;                                                                 \
  } while (0)

#define STAGE_A2(ra, rb, AO)                                                   \
  do {                                                                         \
    gld_lds16(a0p + (ra) * 65536, lds + (AO) + d0 + (ra) * 4096);              \
    gld_lds16(a0p + (rb) * 65536, lds + (AO) + d0 + (rb) * 4096);              \
  } while (0)

// A-frag quad for phase q from buffer bases (bk0,bk1): offsets 4096q, +2048
#define RD_A2(dst, bk0, bk1, O0, O1)                                           \
  do {                                                                         \
    DSR(dst[0], bk0, O0); DSR(dst[1], bk0, O1);                                \
    DSR(dst[2], bk1, O0); DSR(dst[3], bk1, O1);                                \
  } while (0)

// B-frag half (two n-frags j,j+1) from bases: bfr[TB][2j+ks]
#define RD_B2(TB, bk0, bk1, O0, O1, I0)                                        \
  do {                                                                         \
    DSR(bfr[TB][(I0)+0], bk0, O0); DSR(bfr[TB][(I0)+1], bk1, O0);              \
    DSR(bfr[TB][(I0)+2], bk0, O1); DSR(bfr[TB][(I0)+3], bk1, O1);              \
  } while (0)

#define MFMA_PH(q, S, TB)                                                      \
  do {                                                                         \
    __builtin_amdgcn_s_setprio(1);                                             \
    _Pragma("unroll")                                                          \
    for (int j = 0; j < 4; ++j) {                                              \
      acc[2*(q)][j]   = __builtin_amdgcn_mfma_f32_16x16x32_bf16(S[0], bfr[TB][2*j], acc[2*(q)][j],   0, 0, 0); \
      acc[2*(q)+1][j] = __builtin_amdgcn_mfma_f32_16x16x32_bf16(S[1], bfr[TB][2*j], acc[2*(q)+1][j], 0, 0, 0); \
    }                                                                          \
    _Pragma("unroll")                                                          \
    for (int j = 0; j < 4; ++j) {                                              \
      acc[2*(q)][j]   = __builtin_amdgcn_mfma_f32_16x16x32_bf16(S[2], bfr[TB][2*j+1], acc[2*(q)][j],   0, 0, 0); \
      acc[2*(q)+1][j] = __builtin_amdgcn_mfma_f32_16x16x32_bf16(S[3], bfr[TB][2*j+1], acc[2*(q)+1][j], 0, 0, 0); \
    }                                                                          \
    __builtin_amdgcn_s_setprio(0);                                             \
  } while (0)

#define BAR __builtin_amdgcn_s_barrier()

// steady-state K-tile. aC*/aN* = cur/next A bases, bN* = next B bases,
// TBC/TBN = B parities, AO_N/BO_N = next-buffer stage regions.
#define KTILE(aC0, aC1, aN0, aN1, bN0, bN1, TBC, TBN, AO_N, BO_N)              \
  do {                                                                         \
    /* ph0: MFMA q0 (afA); read q1 -> afB; stage B(t+1) */                     \
    RD_A2(afB, aC0, aC1, 4096, 6144);                                          \
    STAGE_B4(BO_N);                                                            \
    LWAIT(4); SCHED0;                                                          \
    MFMA_PH(0, afA, TBC); SCHED0;                                              \
    VWAIT(4);                          /* A_r1,r3(cur) landed */               \
    BAR;                                                                       \
    /* ph1: MFMA q1 (afB); read q2 -> afA; stage A r0,r2 */                    \
    RD_A2(afA, aC0, aC1, 8192, 10240);                                         \
    STAGE_A2(0, 2, AO_N);                                                      \
    LWAIT(4); SCHED0;                                                          \
    MFMA_PH(1, afB, TBC); SCHED0;                                              \
    VWAIT(2);                          /* B(t+1) landed */                     \
    BAR;                                                                       \
    /* ph2: MFMA q2 (afA); read q3 -> afB + B(t+1) half0; stage A r1,r3 */     \
    RD_A2(afB, aC0, aC1, 12288, 14336);                                        \
    RD_B2(TBN, bN0, bN1, 0, 2048, 0);                                          \
    STAGE_A2(1, 3, AO_N); a0p += 64;                                           \
    LWAIT(8); SCHED0;                                                          \
    MFMA_PH(2, afA, TBC); SCHED0;                                              \
    VWAIT(2);                          /* A_r0,r2(t+1) landed */               \
    BAR;                                                                       \
    /* ph3: MFMA q3 (afB); read next q0 -> afA + B(t+1) half1 */               \
    RD_A2(afA, aN0, aN1, 0, 2048);                                             \
    RD_B2(TBN, bN0, bN1, 4096, 6144, 4);                                       \
    LWAIT(8); SCHED0;                                                          \
    MFMA_PH(3, afB, TBC); SCHED0;                                              \
    BAR;                                                                       \
  } while (0)

// last K-tile: no staging, no next-tile reads; drain leftover A_r1,r3
#define KTILE_LAST(aC0, aC1, TBC)                                              \
  do {                                                                         \
    RD_A2(afB, aC0, aC1, 4096, 6144);                                          \
    LWAIT(4); SCHED0;                                                          \
    MFMA_PH(0, afA, TBC); SCHED0;                                              \
    VWAIT(0);                                                                  \
    BAR;                                                                       \
    RD_A2(afA, aC0, aC1, 8192, 10240);                                         \
    LWAIT(4); SCHED0;                                                          \
    MFMA_PH(1, afB, TBC); SCHED0;                                              \
    BAR;                                                                       \
    RD_A2(afB, aC0, aC1, 12288, 14336);                                        \
    LWAIT(4); SCHED0;                                                          \
    MFMA_PH(2, afA, TBC); SCHED0;                                              \
    BAR;                                                                       \
    LWAIT(0); SCHED0;                                                          \
    MFMA_PH(3, afB, TBC);                                                      \
  } while (0)

  // prologue: stage tile 0 -> buf0 in order B0-3, A_r0, A_r2, A_r1, A_r3
  gld_lds16(b0p + 0 * 65536, lds + B0 + d0 + 0 * 4096);
  gld_lds16(b0p + 1 * 65536, lds + B0 + d0 + 1 * 4096);
  gld_lds16(b0p + 2 * 65536, lds + B0 + d0 + 2 * 4096);
  gld_lds16(b0p + 3 * 65536, lds + B0 + d0 + 3 * 4096);
  gld_lds16(a0p + 0 * 65536, lds + A0 + d0 + 0 * 4096);
  gld_lds16(a0p + 2 * 65536, lds + A0 + d0 + 2 * 4096);
  gld_lds16(a0p + 1 * 65536, lds + A0 + d0 + 1 * 4096);
  gld_lds16(a0p + 3 * 65536, lds + A0 + d0 + 3 * 4096);
  a0p += 64; b0p += 64;
  VWAIT(2);                       // B(0)+A_r0,r2 landed; A_r1,r3 in flight
  BAR;
  // pre-read tile0: full B set (parity 0) + ph0 A-frags
  RD_B2(0, uB0k0, uB0k1, 0, 2048, 0);
  RD_B2(0, uB0k0, uB0k1, 4096, 6144, 4);
  RD_A2(afA, uA0k0, uA0k1, 0, 2048);

  for (int it = 0; it < 7; ++it) {       // tiles 0..13
    KTILE(uA0k0, uA0k1, uA1k0, uA1k1, uB1k0, uB1k1, 0, 1, A1, B1);
    KTILE(uA1k0, uA1k1, uA0k0, uA0k1, uB0k0, uB0k1, 1, 0, A0, B0);
  }
  KTILE(uA0k0, uA0k1, uA1k0, uA1k1, uB1k0, uB1k1, 0, 1, A1, B1);  // tile 14
  KTILE_LAST(uA1k0, uA1k1, 1);                                    // tile 15

#undef STAGE_B4
#undef STAGE_A2
#undef RD_A2
#undef RD_B2
#undef MFMA_PH
#undef BAR
#undef KTILE
#undef KTILE_LAST
}

// bijective XCD swizzle for nwg % 8 == 0
__device__ __forceinline__ void xcd_swizzle(int nx, int ny, int& bx, int& by) {
  const int nwg = nx * ny;
  int bid = by * nx + bx;
  bid = (bid & 7) * (nwg >> 3) + (bid >> 3);
  bx = bid % nx;
  by = bid / nx;
}

// GEMM1: X[16384,1024] @ Wcat[3072,1024].T -> Q/K/V stored TRANSPOSED [t][d][b]
__global__ __launch_bounds__(512, 1)
void gemm_qkv(const u16* __restrict__ A, const u16* __restrict__ Bw,
              const float* __restrict__ bq,
              u16* __restrict__ Qt, u16* __restrict__ Kt, u16* __restrict__ Vt) {
  __shared__ __align__(16) u16 lds[65536];   // 128 KiB
  int bx = blockIdx.x, by = blockIdx.y;
  xcd_swizzle(gridDim.x, gridDim.y, bx, by);
  const int n0 = bx * 256;                   // d within QKV-cat (256|1024 ok)
  const int m0 = by * 256;                   // t*1024 + b (256|1024 ok)
  f32x4 acc[8][4];
#pragma unroll
  for (int i = 0; i < 8; ++i)
#pragma unroll
    for (int j = 0; j < 4; ++j) acc[i][j] = (f32x4){0.f, 0.f, 0.f, 0.f};

  mainloop256(A, Bw, lds, m0, n0, acc);
  __syncthreads();   // real fence: all LDS reads retired before scatter reuse

  const int tid  = threadIdx.x;
  const int lane = tid & 63;
  const int w    = tid >> 6;
  const int wm   = w >> 2, wn = w & 3;
  const int colw = lane & 15, roww = (lane >> 4) * 4;
  const int t = m0 >> 10, b0 = m0 & 1023;
  const int sel = n0 >> 10, dbase = n0 & 1023;
  u16* outp = (sel == 0) ? Qt : (sel == 1) ? Kt : Vt;

  // scatter BOTH wm-halves concurrently: region[wm] = 64KiB at wm*32768 u16.
  // phys byte in region = d*256 + (Lbyte ^ ((d&7)<<4)); paired 8B stores.
  {
    char* reg = (char*)(lds + wm * 32768);
#pragma unroll
    for (int j = 0; j < 4; ++j) {
      const int dl = wn * 64 + j * 16 + colw;
      const float badd = (sel == 0) ? bq[dbase + dl] : 0.f;
      char* rowp = reg + (unsigned)dl * 256;
      const unsigned sx = ((unsigned)dl & 7) << 4;
#pragma unroll
      for (int i = 0; i < 8; ++i) {
        const int bl = i * 16 + roww;           // multiple of 4
        uint2 pv;
        pv.x = (unsigned)f2bf(acc[i][j][0] + badd)
             | ((unsigned)f2bf(acc[i][j][1] + badd) << 16);
        pv.y = (unsigned)f2bf(acc[i][j][2] + badd)
             | ((unsigned)f2bf(acc[i][j][3] + badd) << 16);
        *(uint2*)(rowp + (((unsigned)bl * 2) ^ sx)) = pv;
      }
    }
  }
  __syncthreads();
  // writeout: 2 regions x 4096 uint4, coalesced rows into [t][d][b]
#pragma unroll
  for (int pass = 0; pass < 2; ++pass) {
    const char* regp = (const char*)(lds + pass * 32768);
#pragma unroll
    for (int rr = 0; rr < 8; ++rr) {
      const int slot = rr * 512 + tid;          // 4096 slots = 256 rows x 16
      const int row = slot >> 4, c16 = slot & 15;
      const uint4 v = *(const uint4*)(regp + (unsigned)row * 256
                                      + (((unsigned)c16 * 16) ^ (((unsigned)row & 7) << 4)));
      *(uint4*)(outp + ((size_t)t << 20) + (size_t)(dbase + row) * 1024
                + b0 + pass * 128 + c16 * 8) = v;
    }
  }
}

// GEMM2: ctx[16384,1024] @ Wo[1024,1024].T + bo -> fp32 out
__global__ __launch_bounds__(512, 1)
void gemm_out(const u16* __restrict__ A, const u16* __restrict__ Bw,
              const float* __restrict__ bo, float* __restrict__ out) {
  __shared__ __align__(16) u16 lds[65536];
  int bx = blockIdx.x, by = blockIdx.y;
  xcd_swizzle(gridDim.x, gridDim.y, bx, by);
  const int n0 = bx * 256;
  const int m0 = by * 256;
  f32x4 acc[8][4];
#pragma unroll
  for (int i = 0; i < 8; ++i)
#pragma unroll
    for (int j = 0; j < 4; ++j) acc[i][j] = (f32x4){0.f, 0.f, 0.f, 0.f};

  mainloop256(A, Bw, lds, m0, n0, acc);
  // epilogue touches no LDS -> no extra fence needed

  const int lane = threadIdx.x & 63;
  const int w    = threadIdx.x >> 6;
  const int wm   = w >> 2, wn = w & 3;
  const int colw = lane & 15, roww = (lane >> 4) * 4;
#pragma unroll
  for (int j = 0; j < 4; ++j) {
    const int gn = n0 + wn * 64 + j * 16 + colw;
    const float bov = bo[gn];
#pragma unroll
    for (int i = 0; i < 8; ++i) {
      const int gm = m0 + wm * 128 + i * 16 + roww;
#pragma unroll
      for (int r = 0; r < 4; ++r)
        out[(size_t)(gm + r) * 1024 + gn] = acc[i][j][r] + bov;
    }
  }
}

// ---------------------------------------------------------------- attention
// attn6: one block per (t,h); 512 threads x 2 b's each (full b=0..1023).
// Each (t,h)'s K/V rel-slice (2MB) is read exactly once per block; blocks
// grouped so the 16 same-h blocks (sharing the 16-table x 64-d slice) land
// on one XCD (h = (bid&7)*2 + (bid>>3)/16) and stream it through L2 in
// lockstep d-order. Loads are uint (2 bf16 = 2 b's), 256B/wave coalesced.
__global__ __launch_bounds__(512)
void attn6(const u16* __restrict__ Qt, const u16* __restrict__ Kt,
           const u16* __restrict__ Vt,
           const float* __restrict__ relw, const int* __restrict__ rel_idx,
           const float* __restrict__ bk, const float* __restrict__ bv,
           u16* __restrict__ ctx) {
  const int tid = threadIdx.x;
  const int bid = blockIdx.x;               // 0..255
  const int h = (bid & 7) * 2 + ((bid >> 3) >> 4);
  const int t = (bid >> 3) & 15;
  const int hd = h * 64;
  const int b0 = tid * 2;                   // this thread's b-pair

  __shared__ float bks[64], bvs[64], rws[8];
  __shared__ int   rids[8];
  if (tid < 64) { bks[tid] = bk[hd + tid]; bvs[tid] = bv[hd + tid]; }
  else if (tid < 72) { rws[tid - 64] = relw[t * 8 + (tid - 64)];
                       rids[tid - 64] = rel_idx[t * 8 + (tid - 64)]; }
  __syncthreads();

  // element offsets at d=0 into [t][1024 d][1024 b] arrays (b0 even -> 4B ok)
  const unsigned qoff = ((unsigned)t << 20) + ((unsigned)hd << 10) + (unsigned)b0;
  unsigned koff[8];
#pragma unroll
  for (int r = 0; r < 8; ++r)
    koff[r] = ((unsigned)rids[r] << 20) + ((unsigned)hd << 10) + (unsigned)b0;

  // ---- scores (2 b's per thread)
  float a0[8], a1[8];
#pragma unroll
  for (int r = 0; r < 8; ++r) { a0[r] = 0.f; a1[r] = 0.f; }
  float qbk0 = 0.f, qbk1 = 0.f;
#pragma unroll 4
  for (int d = 0; d < 64; ++d) {
    const unsigned qv = *(const unsigned*)(Qt + qoff + d * 1024);
    const float q0 = lo_f(qv), q1 = hi_f(qv);
    qbk0 += q0 * bks[d];
    qbk1 += q1 * bks[d];
#pragma unroll
    for (int r = 0; r < 8; ++r) {
      const unsigned kv = *(const unsigned*)(Kt + koff[r] + d * 1024);
      a0[r] += q0 * lo_f(kv);
      a1[r] += q1 * hi_f(kv);
    }
  }

  // ---- softmax -> w[j][r] = attn_r * rw_r  (independent per b)
  float w0[8], w1[8];
  {
    float s0[8], s1[8], m0 = -1e30f, m1 = -1e30f;
#pragma unroll
    for (int r = 0; r < 8; ++r) {
      s0[r] = (rws[r] * a0[r] + qbk0) * 0.125f;
      s1[r] = (rws[r] * a1[r] + qbk1) * 0.125f;
      m0 = fmaxf(m0, s0[r]);
      m1 = fmaxf(m1, s1[r]);
    }
    float t0 = 0.f, t1 = 0.f;
#pragma unroll
    for (int r = 0; r < 8; ++r) {
      s0[r] = __expf(s0[r] - m0); t0 += s0[r];
      s1[r] = __expf(s1[r] - m1); t1 += s1[r];
    }
    const float i0 = 1.f / t0, i1 = 1.f / t1;
#pragma unroll
    for (int r = 0; r < 8; ++r) {
      w0[r] = s0[r] * i0 * rws[r];
      w1[r] = s1[r] * i1 * rws[r];
    }
  }

  // ---- context: 8 d's at a time, direct uint4 stores (no LDS staging)
  u16* cp0 = ctx + ((size_t)(t * 1024 + b0)) * 1024 + hd;
  u16* cp1 = cp0 + 1024;
  for (int dblk = 0; dblk < 8; ++dblk) {
    float o0[8], o1[8];
#pragma unroll
    for (int dp = 0; dp < 8; ++dp) {
      const float bvv = bvs[dblk * 8 + dp];
      o0[dp] = bvv; o1[dp] = bvv;
    }
#pragma unroll
    for (int dp = 0; dp < 8; ++dp) {
      const int d = dblk * 8 + dp;
#pragma unroll
      for (int r = 0; r < 8; ++r) {
        const unsigned vv = *(const unsigned*)(Vt + koff[r] + d * 1024);
        o0[dp] += w0[r] * lo_f(vv);
        o1[dp] += w1[r] * hi_f(vv);
      }
    }
    uint4 pv0, pv1;
    pv0.x = (unsigned)f2bf(o0[0]) | ((unsigned)f2bf(o0[1]) << 16);
    pv0.y = (unsigned)f2bf(o0[2]) | ((unsigned)f2bf(o0[3]) << 16);
    pv0.z = (unsigned)f2bf(o0[4]) | ((unsigned)f2bf(o0[5]) << 16);
    pv0.w = (unsigned)f2bf(o0[6]) | ((unsigned)f2bf(o0[7]) << 16);
    pv1.x = (unsigned)f2bf(o1[0]) | ((unsigned)f2bf(o1[1]) << 16);
    pv1.y = (unsigned)f2bf(o1[2]) | ((unsigned)f2bf(o1[3]) << 16);
    pv1.z = (unsigned)f2bf(o1[4]) | ((unsigned)f2bf(o1[5]) << 16);
    pv1.w = (unsigned)f2bf(o1[6]) | ((unsigned)f2bf(o1[7]) << 16);
    *(uint4*)(cp0 + dblk * 8) = pv0;
    *(uint4*)(cp1 + dblk * 8) = pv1;
  }
}

// ---------------------------------------------------------------- launch

extern "C" void kernel_launch(void* const* d_in, const int* in_sizes, int n_in,
                              void* d_out, int out_size, void* d_ws, size_t ws_size,
                              hipStream_t stream) {
  const float* table = (const float*)d_in[0];
  const float* rele  = (const float*)d_in[1];
  const int*   ridx  = (const int*)d_in[2];
  const float* Wq    = (const float*)d_in[3];
  const float* bq    = (const float*)d_in[4];
  const float* Wk    = (const float*)d_in[5];
  const float* bk    = (const float*)d_in[6];
  const float* Wv    = (const float*)d_in[7];
  const float* bv    = (const float*)d_in[8];
  const float* Wo    = (const float*)d_in[9];
  const float* bo    = (const float*)d_in[10];
  const float* wr    = (const float*)d_in[11];
  const float* br    = (const float*)d_in[12];
  float* out = (float*)d_out;

  char* ws = (char*)d_ws;
  const size_t MB = 1024 * 1024;
  u16*  Xbf  = (u16*)(ws);                    // 32 MB  [16384,1024] bf16 (also ctx)
  u16*  Kt   = (u16*)(ws + 32  * MB);         // 32 MB  [16][1024 d][1024 b]
  u16*  Vt   = (u16*)(ws + 64  * MB);         // 32 MB
  u16*  Qt   = (u16*)(ws + 96  * MB);         // 32 MB
  u16*  Wcat = (u16*)(ws + 128 * MB);         // 6 MB   [3072,1024] (Wq|Wk|Wv)
  u16*  Wob  = (u16*)(ws + 134 * MB);         // 2 MB
  float* relw = (float*)(ws + 136 * MB);      // 512 B
  u16*  ctxb = Xbf;                           // reuse: Xbf dead after gemm_qkv

  relw_kernel<<<128, 64, 0, stream>>>(rele, wr, br, relw);
  cvt_f32_bf16<<<16384, 256, 0, stream>>>(table, Xbf, 4194304);
  cvt_w4<<<4096, 256, 0, stream>>>(Wq, Wk, Wv, Wo, Wcat, Wob);

  gemm_qkv<<<dim3(12, 64), 512, 0, stream>>>(Xbf, Wcat, bq, Qt, Kt, Vt);
  attn6<<<256, 512, 0, stream>>>(Qt, Kt, Vt, relw, ridx, bk, bv, ctxb);
  gemm_out<<<dim3(4, 64), 512, 0, stream>>>(ctxb, Wob, bo, out);
}